// Round 10
// baseline (159.801 us; speedup 1.0000x reference)
//
#include <hip/hip_runtime.h>
#include <hip/hip_bf16.h>

// Weighted BCE over predict [N=8, C=19, H=512, W=1024] fp32 probs,
// target [N,H,W] int32 labels -> single fp32 scalar.
//
// result = (neg_num*S_pos + pos_num*S_neg) / ((pos_num+neg_num)*mask_cnt*C)
//
// R9 lesson: nontemporal loads bypassed L3 fill -> lost the ~40%
// cross-replay Infinity-Cache reuse, +30us. R10: same fused structure
// (labels 2 x int4 once per thread, counts in-kernel, pack kernel gone,
// lockstep-linear sweep, 8-deep load batches) with PLAIN loads.

constexpr int CLS    = 19;
constexpr int HWSZ   = 512 * 1024;        // pixels per plane
constexpr int CHW4   = HWSZ / 4;          // float4/int4 chunks per plane
constexpr int SLABC  = CLS * CHW4;        // chunks per image
constexpr int IGNORE = 255;
constexpr int GPI    = 65536;             // threads per image = CHW4/2
constexpr int NWIN   = 2 * CLS;           // 38 windows per slab

// ws: f[0]=S_valid_log2, f[1]=S_neg_log2, u[2]=pos, u[3]=neg, u[4]=mask

__global__ void bce_init(float* wsf) {
    if (threadIdx.x < 8) wsf[threadIdx.x] = 0.0f;
}

// ---- fused hot kernel: labels once per thread, counts in-kernel ----
__global__ __launch_bounds__(256) void bce_fused(
    const float4* __restrict__ pred4,
    const int4*   __restrict__ tgt4,
    float* __restrict__ wsf, unsigned* __restrict__ wsu)
{
    const int b  = blockIdx.x;
    const int ni = b >> 8;                         // image (scalar)
    const int g  = ((b & 255) << 8) | threadIdx.x; // [0, GPI)

    const float4* slab = pred4 + (size_t)ni * SLABC;
    const int4*   labs = tgt4  + (size_t)ni * CHW4;

    // labels for this thread's 8 pixels (hw4 = g and g+GPI), loaded ONCE;
    // each int4 is owned by exactly one thread per image -> counts exact.
    int4 t0 = labs[g];
    int4 t1 = labs[g + GPI];
    int   t[8] = { t0.x, t0.y, t0.z, t0.w, t1.x, t1.y, t1.z, t1.w };
    float wv[8], wn[8];
    unsigned cp = 0, cn = 0, cm = 0;
    #pragma unroll
    for (int j = 0; j < 8; ++j) {
        bool val = (t[j] >= 0) && (t[j] != IGNORE);
        cp += (t[j] > 0)  ? 1u : 0u;     // reference counts ALL t>0 as pos
        cn += (t[j] == 0) ? 1u : 0u;
        cm += val         ? 1u : 0u;
        wv[j] = val         ? 1.0f : 0.0f;
        wn[j] = (t[j] == 0) ? 1.0f : 0.0f;
        // invalid labels (255/neg) never equal c in [0,19) -> x=1-p, weight 0
    }

    float sv = 0.f, sn = 0.f;

    // 38 windows in batches of 8,8,8,8,6; all indices compile-time.
    #pragma unroll
    for (int kb = 0; kb < NWIN; kb += 8) {
        const int cnt = (NWIN - kb) < 8 ? (NWIN - kb) : 8;
        float4 p[8];
        #pragma unroll
        for (int m = 0; m < 8; ++m)
            if (m < cnt) p[m] = slab[(size_t)(kb + m) * GPI + g];
        #pragma unroll
        for (int m = 0; m < 8; ++m) {
            if (m < cnt) {
                const int k  = kb + m;
                const int c  = k >> 1;            // plane, compile-time
                const int wo = (k & 1) * 4;
                const float pj[4] = { p[m].x, p[m].y, p[m].z, p[m].w };
                #pragma unroll
                for (int j = 0; j < 4; ++j) {
                    float q = 1.0f - pj[j];
                    float x = (t[wo + j] == c) ? pj[j] : q;  // x >= 1e-4
                    float l = __log2f(x);
                    sv = fmaf(wv[wo + j], l, sv);
                    sn = fmaf(wn[wo + j], l, sn);
                }
            }
        }
    }

    // ---- wave reduction ----
    #pragma unroll
    for (int off = 32; off > 0; off >>= 1) {
        sv += __shfl_down(sv, off);
        sn += __shfl_down(sn, off);
        cp += __shfl_down(cp, off);
        cn += __shfl_down(cn, off);
        cm += __shfl_down(cm, off);
    }
    __shared__ float    lsv[4], lsn[4];
    __shared__ unsigned lcp[4], lcn[4], lcm[4];
    int lane = threadIdx.x & 63, wid = threadIdx.x >> 6;
    if (lane == 0) {
        lsv[wid] = sv; lsn[wid] = sn;
        lcp[wid] = cp; lcn[wid] = cn; lcm[wid] = cm;
    }
    __syncthreads();
    if (threadIdx.x == 0) {
        float bv = 0.f, bn = 0.f;
        unsigned up = 0, un = 0, um = 0;
        #pragma unroll
        for (int i = 0; i < 4; ++i) {
            bv += lsv[i]; bn += lsn[i];
            up += lcp[i]; un += lcn[i]; um += lcm[i];
        }
        atomicAdd(&wsf[0], bv);
        atomicAdd(&wsf[1], bn);
        atomicAdd(&wsu[2], up);
        atomicAdd(&wsu[3], un);
        atomicAdd(&wsu[4], um);
    }
}

// ---- general fallback (R4 structure) ----
__global__ __launch_bounds__(256) void bce_count(
    const int* __restrict__ tgt, unsigned* __restrict__ wsu, int npix4)
{
    int tid    = blockIdx.x * blockDim.x + threadIdx.x;
    int stride = gridDim.x * blockDim.x;
    unsigned cp = 0, cn = 0, cm = 0;
    for (int i = tid; i < npix4; i += stride) {
        int4 t4 = ((const int4*)tgt)[i];
        int  t[4] = { t4.x, t4.y, t4.z, t4.w };
        #pragma unroll
        for (int j = 0; j < 4; ++j) {
            cp += (t[j] > 0) ? 1u : 0u;
            cn += (t[j] == 0) ? 1u : 0u;
            cm += ((t[j] >= 0) && (t[j] != IGNORE)) ? 1u : 0u;
        }
    }
    #pragma unroll
    for (int off = 32; off > 0; off >>= 1) {
        cp += __shfl_down(cp, off);
        cn += __shfl_down(cn, off);
        cm += __shfl_down(cm, off);
    }
    __shared__ unsigned lcp[4], lcn[4], lcm[4];
    int lane = threadIdx.x & 63, wid = threadIdx.x >> 6;
    if (lane == 0) { lcp[wid] = cp; lcn[wid] = cn; lcm[wid] = cm; }
    __syncthreads();
    if (threadIdx.x == 0) {
        unsigned up = 0, un = 0, um = 0;
        #pragma unroll
        for (int i = 0; i < 4; ++i) { up += lcp[i]; un += lcn[i]; um += lcm[i]; }
        atomicAdd(&wsu[2], up);
        atomicAdd(&wsu[3], un);
        atomicAdd(&wsu[4], um);
    }
}

__global__ __launch_bounds__(256) void bce_stream_div(
    const float* __restrict__ pred,
    const int*   __restrict__ tgt,
    float*       __restrict__ wsf,
    int nChunks)
{
    const int tloc = threadIdx.x;
    float sv = 0.f, sn = 0.f;
    for (int base = blockIdx.x * 1024; base < nChunks; base += gridDim.x * 1024) {
        #pragma unroll
        for (int m = 0; m < 4; ++m) {
            int f = base + m * 256 + tloc;
            if (f >= nChunks) break;
            int plane   = f >> 17;
            int hw4     = f & (CHW4 - 1);
            unsigned ni = (unsigned)plane / (unsigned)CLS;
            int c       = plane - (int)ni * CLS;
            float4 p4 = ((const float4*)pred)[f];
            int4   t4 = ((const int4*)tgt)[(int)ni * CHW4 + hw4];
            const int   tj[4] = { t4.x, t4.y, t4.z, t4.w };
            const float pj[4] = { p4.x, p4.y, p4.z, p4.w };
            #pragma unroll
            for (int j = 0; j < 4; ++j) {
                bool valid = (tj[j] >= 0) && (tj[j] != IGNORE);
                float wvx = valid ? 1.0f : 0.0f;
                float wnx = (tj[j] == 0) ? 1.0f : 0.0f;
                float q = 1.0f - pj[j];
                float x = (tj[j] == c) ? pj[j] : q;
                x = fminf(fmaxf(x, 1e-12f), 1.0f);
                float l = __log2f(x);
                sv = fmaf(wvx, l, sv);
                sn = fmaf(wnx, l, sn);
            }
        }
    }
    #pragma unroll
    for (int off = 32; off > 0; off >>= 1) {
        sv += __shfl_down(sv, off);
        sn += __shfl_down(sn, off);
    }
    __shared__ float lsv[4], lsn[4];
    int lane = threadIdx.x & 63, wid = threadIdx.x >> 6;
    if (lane == 0) { lsv[wid] = sv; lsn[wid] = sn; }
    __syncthreads();
    if (threadIdx.x == 0) {
        float bv = 0.f, bn = 0.f;
        #pragma unroll
        for (int i = 0; i < 4; ++i) { bv += lsv[i]; bn += lsn[i]; }
        atomicAdd(&wsf[0], bv);
        atomicAdd(&wsf[1], bn);
    }
}

__global__ void bce_final(const float* wsf, const unsigned* wsu, float* out) {
    if (threadIdx.x == 0 && blockIdx.x == 0) {
        const double LN2 = 0.6931471805599453;
        double svld = (double)wsf[0];          // sum log2 over valid pixels
        double sngl = (double)wsf[1];          // sum log2 over t==0 pixels
        double spos = svld - sngl;             // valid & t>0
        double pn   = (double)wsu[2];
        double nn   = (double)wsu[3];
        double mk   = (double)wsu[4];
        double sum  = pn + nn;
        double denom = sum * mk * (double)CLS;
        out[0] = (denom > 0.0)
                   ? (float)(-LN2 * (nn * spos + pn * sngl) / denom)
                   : 0.0f;
    }
}

extern "C" void kernel_launch(void* const* d_in, const int* in_sizes, int n_in,
                              void* d_out, int out_size, void* d_ws, size_t ws_size,
                              hipStream_t stream) {
    const float* pred = (const float*)d_in[0];
    const int*   tgt  = (const int*)d_in[1];
    float*       out  = (float*)d_out;

    float*    wsf = (float*)d_ws;
    unsigned* wsu = (unsigned*)d_ws;

    int nElem = in_sizes[0];          // 8*19*512*1024
    int npix  = in_sizes[1];          // 8*512*1024
    int npix4 = npix >> 2;

    bool fast = (nElem == 8 * SLABC * 4) && (npix == 8 * HWSZ);

    bce_init<<<1, 64, 0, stream>>>(wsf);
    if (fast) {
        bce_fused<<<8 * 256, 256, 0, stream>>>((const float4*)pred,
                                               (const int4*)tgt, wsf, wsu);
    } else {
        int nChunks = nElem >> 2;
        bce_count<<<1024, 256, 0, stream>>>(tgt, wsu, npix4);
        bce_stream_div<<<2048, 256, 0, stream>>>(pred, tgt, wsf, nChunks);
    }
    bce_final<<<1, 64, 0, stream>>>(wsf, wsu, out);
}

// Round 11
// 68.290 us; speedup vs baseline: 2.3400x; 2.3400x over previous
//
#include <hip/hip_runtime.h>
#include <hip/hip_bf16.h>

// Weighted BCE over predict [N=8, C=19, H=512, W=1024] fp32 probs,
// target [N,H,W] int32 labels -> single fp32 scalar.
//
// result = (neg_num*S_pos + pos_num*S_neg) / ((pos_num+neg_num)*mask_cnt*C)
//
// R9/R10 lesson: fusing label-read+counts into the sweep was the regression
// (-33us), not nt: fused kernel holds 27+ extra live VGPRs across all 38
// windows + reads 4x larger raw target. R11: revert to R7's 3-stage
// structure (pack -> sweep -> final), best known at 126.5us, and remove
// fixed overhead: per-block PARTIAL writes instead of atomics ->
// no zero-init kernel needed (unconditional writes), 3 kernels total.

constexpr int CLS    = 19;
constexpr int HWSZ   = 512 * 1024;        // pixels per plane
constexpr int CHW4   = HWSZ / 4;          // float4/int4 chunks per plane
constexpr int SLABC  = CLS * CHW4;        // chunks per image
constexpr int IGNORE = 255;
constexpr int GPI    = 65536;             // threads per image = CHW4/2
constexpr int NWIN   = 2 * CLS;           // 38 windows per slab
constexpr int GRID_P = 1024;              // pack grid
constexpr int GRID_S = 2048;              // sweep grid

// fast-path ws layout:
//   [0, 16KB)      float  fpart[2*GRID_S]   (sv, sn per sweep block)
//   [16KB, 28KB)   uint   upart[3*GRID_P]   (cp, cn, cm per pack block)
//   [32KB, +npix)  packed labels, 1 byte/pixel
// fallback ws layout: f[0]=S_valid, f[1]=S_neg, u[2..4]=counts (atomics)

__global__ void bce_init(float* wsf) {
    if (threadIdx.x < 8) wsf[threadIdx.x] = 0.0f;
}

// ---- pack target to bytes + per-block count partials ----
__global__ __launch_bounds__(256) void bce_pack(
    const int* __restrict__ tgt, unsigned* __restrict__ tgtbw,
    unsigned* __restrict__ upart, int npix4)
{
    int tid    = blockIdx.x * blockDim.x + threadIdx.x;
    int stride = gridDim.x * blockDim.x;
    unsigned cp = 0, cn = 0, cm = 0;
    for (int i = tid; i < npix4; i += stride) {
        int4 t4 = ((const int4*)tgt)[i];
        int  t[4] = { t4.x, t4.y, t4.z, t4.w };
        unsigned w = 0;
        #pragma unroll
        for (int j = 0; j < 4; ++j) {
            int  tj  = t[j];
            bool val = (tj >= 0) && (tj != IGNORE);
            cp += (tj > 0)  ? 1u : 0u;      // reference counts ALL t>0 as pos
            cn += (tj == 0) ? 1u : 0u;
            cm += val       ? 1u : 0u;
            unsigned b = val ? (unsigned)min(tj, 29) : 30u;
            w |= b << (8 * j);
        }
        tgtbw[i] = w;
    }
    #pragma unroll
    for (int off = 32; off > 0; off >>= 1) {
        cp += __shfl_down(cp, off);
        cn += __shfl_down(cn, off);
        cm += __shfl_down(cm, off);
    }
    __shared__ unsigned lcp[4], lcn[4], lcm[4];
    int lane = threadIdx.x & 63, wid = threadIdx.x >> 6;
    if (lane == 0) { lcp[wid] = cp; lcn[wid] = cn; lcm[wid] = cm; }
    __syncthreads();
    if (threadIdx.x == 0) {
        unsigned up = 0, un = 0, um = 0;
        #pragma unroll
        for (int i = 0; i < 4; ++i) { up += lcp[i]; un += lcn[i]; um += lcm[i]; }
        upart[3 * blockIdx.x + 0] = up;
        upart[3 * blockIdx.x + 1] = un;
        upart[3 * blockIdx.x + 2] = um;
    }
}

// ---- hot kernel: lockstep-linear sweep, 8-deep load batches ----
__global__ __launch_bounds__(256) void bce_sweep(
    const float4*   __restrict__ pred4,
    const unsigned* __restrict__ tgtw,    // packed labels as dwords
    float* __restrict__ fpart)
{
    const int b  = blockIdx.x;
    const int ni = b >> 8;                         // image (scalar)
    const int g  = ((b & 255) << 8) | threadIdx.x; // [0, GPI)

    const float4*   slab = pred4 + (size_t)ni * SLABC;
    const unsigned* labw = tgtw  + (size_t)ni * CHW4;

    // labels once: window k reads chunk k*GPI+g, hw4 = (k&1)*GPI + g
    unsigned lw0 = labw[g];
    unsigned lw1 = labw[g + GPI];
    unsigned bj[8]; float wv[8], wn[8];
    #pragma unroll
    for (int j = 0; j < 4; ++j) {
        unsigned b0 = (lw0 >> (8 * j)) & 0xffu;
        unsigned b1 = (lw1 >> (8 * j)) & 0xffu;
        bj[j]     = b0;  bj[4 + j] = b1;
        wv[j]     = (b0 < 30u) ? 1.0f : 0.0f;
        wn[j]     = (b0 == 0u) ? 1.0f : 0.0f;
        wv[4 + j] = (b1 < 30u) ? 1.0f : 0.0f;
        wn[4 + j] = (b1 == 0u) ? 1.0f : 0.0f;
    }

    float sv = 0.f, sn = 0.f;

    // 38 windows in batches of 8,8,8,8,6; all indices compile-time.
    #pragma unroll
    for (int kb = 0; kb < NWIN; kb += 8) {
        const int cnt = (NWIN - kb) < 8 ? (NWIN - kb) : 8;
        float4 p[8];
        #pragma unroll
        for (int m = 0; m < 8; ++m)
            if (m < cnt) p[m] = slab[(size_t)(kb + m) * GPI + g];
        #pragma unroll
        for (int m = 0; m < 8; ++m) {
            if (m < cnt) {
                const int      k  = kb + m;
                const unsigned c  = (unsigned)(k >> 1);   // plane (const)
                const int      wo = (k & 1) * 4;
                const float pj[4] = { p[m].x, p[m].y, p[m].z, p[m].w };
                #pragma unroll
                for (int j = 0; j < 4; ++j) {
                    float q = 1.0f - pj[j];
                    float x = (bj[wo + j] == c) ? pj[j] : q;  // x>=1e-4
                    float l = __log2f(x);
                    sv = fmaf(wv[wo + j], l, sv);
                    sn = fmaf(wn[wo + j], l, sn);
                }
            }
        }
    }

    #pragma unroll
    for (int off = 32; off > 0; off >>= 1) {
        sv += __shfl_down(sv, off);
        sn += __shfl_down(sn, off);
    }
    __shared__ float lsv[4], lsn[4];
    int lane = threadIdx.x & 63, wid = threadIdx.x >> 6;
    if (lane == 0) { lsv[wid] = sv; lsn[wid] = sn; }
    __syncthreads();
    if (threadIdx.x == 0) {
        float bv = 0.f, bn = 0.f;
        #pragma unroll
        for (int i = 0; i < 4; ++i) { bv += lsv[i]; bn += lsn[i]; }
        fpart[2 * b + 0] = bv;
        fpart[2 * b + 1] = bn;
    }
}

// ---- final: reduce partials, compute result ----
__global__ __launch_bounds__(256) void bce_final_fast(
    const float* __restrict__ fpart, const unsigned* __restrict__ upart,
    float* __restrict__ out)
{
    int tid = threadIdx.x;
    float sv = 0.f, sn = 0.f;
    for (int i = tid; i < GRID_S; i += 256) {
        sv += fpart[2 * i + 0];
        sn += fpart[2 * i + 1];
    }
    unsigned cp = 0, cn = 0, cm = 0;
    for (int i = tid; i < GRID_P; i += 256) {
        cp += upart[3 * i + 0];
        cn += upart[3 * i + 1];
        cm += upart[3 * i + 2];
    }
    #pragma unroll
    for (int off = 32; off > 0; off >>= 1) {
        sv += __shfl_down(sv, off);
        sn += __shfl_down(sn, off);
        cp += __shfl_down(cp, off);
        cn += __shfl_down(cn, off);
        cm += __shfl_down(cm, off);
    }
    __shared__ float    lsv[4], lsn[4];
    __shared__ unsigned lcp[4], lcn[4], lcm[4];
    int lane = tid & 63, wid = tid >> 6;
    if (lane == 0) {
        lsv[wid] = sv; lsn[wid] = sn;
        lcp[wid] = cp; lcn[wid] = cn; lcm[wid] = cm;
    }
    __syncthreads();
    if (tid == 0) {
        float bv = 0.f, bn = 0.f;
        unsigned up = 0, un = 0, um = 0;
        #pragma unroll
        for (int i = 0; i < 4; ++i) {
            bv += lsv[i]; bn += lsn[i];
            up += lcp[i]; un += lcn[i]; um += lcm[i];
        }
        const double LN2 = 0.6931471805599453;
        double svld = (double)bv;           // sum log2 over valid pixels
        double sngl = (double)bn;           // sum log2 over t==0 pixels
        double spos = svld - sngl;          // valid & t>0
        double pn = (double)up, nn = (double)un, mk = (double)um;
        double denom = (pn + nn) * mk * (double)CLS;
        out[0] = (denom > 0.0)
                   ? (float)(-LN2 * (nn * spos + pn * sngl) / denom)
                   : 0.0f;
    }
}

// ---- general fallback (R4 structure, atomics) ----
__global__ __launch_bounds__(256) void bce_count(
    const int* __restrict__ tgt, unsigned* __restrict__ wsu, int npix4)
{
    int tid    = blockIdx.x * blockDim.x + threadIdx.x;
    int stride = gridDim.x * blockDim.x;
    unsigned cp = 0, cn = 0, cm = 0;
    for (int i = tid; i < npix4; i += stride) {
        int4 t4 = ((const int4*)tgt)[i];
        int  t[4] = { t4.x, t4.y, t4.z, t4.w };
        #pragma unroll
        for (int j = 0; j < 4; ++j) {
            cp += (t[j] > 0) ? 1u : 0u;
            cn += (t[j] == 0) ? 1u : 0u;
            cm += ((t[j] >= 0) && (t[j] != IGNORE)) ? 1u : 0u;
        }
    }
    #pragma unroll
    for (int off = 32; off > 0; off >>= 1) {
        cp += __shfl_down(cp, off);
        cn += __shfl_down(cn, off);
        cm += __shfl_down(cm, off);
    }
    __shared__ unsigned lcp[4], lcn[4], lcm[4];
    int lane = threadIdx.x & 63, wid = threadIdx.x >> 6;
    if (lane == 0) { lcp[wid] = cp; lcn[wid] = cn; lcm[wid] = cm; }
    __syncthreads();
    if (threadIdx.x == 0) {
        unsigned up = 0, un = 0, um = 0;
        #pragma unroll
        for (int i = 0; i < 4; ++i) { up += lcp[i]; un += lcn[i]; um += lcm[i]; }
        atomicAdd(&wsu[2], up);
        atomicAdd(&wsu[3], un);
        atomicAdd(&wsu[4], um);
    }
}

__global__ __launch_bounds__(256) void bce_stream_div(
    const float* __restrict__ pred,
    const int*   __restrict__ tgt,
    float*       __restrict__ wsf,
    int nChunks)
{
    const int tloc = threadIdx.x;
    float sv = 0.f, sn = 0.f;
    for (int base = blockIdx.x * 1024; base < nChunks; base += gridDim.x * 1024) {
        #pragma unroll
        for (int m = 0; m < 4; ++m) {
            int f = base + m * 256 + tloc;
            if (f >= nChunks) break;
            int plane   = f >> 17;
            int hw4     = f & (CHW4 - 1);
            unsigned ni = (unsigned)plane / (unsigned)CLS;
            int c       = plane - (int)ni * CLS;
            float4 p4 = ((const float4*)pred)[f];
            int4   t4 = ((const int4*)tgt)[(int)ni * CHW4 + hw4];
            const int   tj[4] = { t4.x, t4.y, t4.z, t4.w };
            const float pj[4] = { p4.x, p4.y, p4.z, p4.w };
            #pragma unroll
            for (int j = 0; j < 4; ++j) {
                bool valid = (tj[j] >= 0) && (tj[j] != IGNORE);
                float wvx = valid ? 1.0f : 0.0f;
                float wnx = (tj[j] == 0) ? 1.0f : 0.0f;
                float q = 1.0f - pj[j];
                float x = (tj[j] == c) ? pj[j] : q;
                x = fminf(fmaxf(x, 1e-12f), 1.0f);
                float l = __log2f(x);
                sv = fmaf(wvx, l, sv);
                sn = fmaf(wnx, l, sn);
            }
        }
    }
    #pragma unroll
    for (int off = 32; off > 0; off >>= 1) {
        sv += __shfl_down(sv, off);
        sn += __shfl_down(sn, off);
    }
    __shared__ float lsv[4], lsn[4];
    int lane = threadIdx.x & 63, wid = threadIdx.x >> 6;
    if (lane == 0) { lsv[wid] = sv; lsn[wid] = sn; }
    __syncthreads();
    if (threadIdx.x == 0) {
        float bv = 0.f, bn = 0.f;
        #pragma unroll
        for (int i = 0; i < 4; ++i) { bv += lsv[i]; bn += lsn[i]; }
        atomicAdd(&wsf[0], bv);
        atomicAdd(&wsf[1], bn);
    }
}

__global__ void bce_final(const float* wsf, const unsigned* wsu, float* out) {
    if (threadIdx.x == 0 && blockIdx.x == 0) {
        const double LN2 = 0.6931471805599453;
        double svld = (double)wsf[0];
        double sngl = (double)wsf[1];
        double spos = svld - sngl;
        double pn   = (double)wsu[2];
        double nn   = (double)wsu[3];
        double mk   = (double)wsu[4];
        double denom = (pn + nn) * mk * (double)CLS;
        out[0] = (denom > 0.0)
                   ? (float)(-LN2 * (nn * spos + pn * sngl) / denom)
                   : 0.0f;
    }
}

extern "C" void kernel_launch(void* const* d_in, const int* in_sizes, int n_in,
                              void* d_out, int out_size, void* d_ws, size_t ws_size,
                              hipStream_t stream) {
    const float* pred = (const float*)d_in[0];
    const int*   tgt  = (const int*)d_in[1];
    float*       out  = (float*)d_out;

    int nElem = in_sizes[0];          // 8*19*512*1024
    int npix  = in_sizes[1];          // 8*512*1024
    int npix4 = npix >> 2;

    bool fast = (nElem == 8 * SLABC * 4) && (npix == 8 * HWSZ)
                && (ws_size >= 32768 + (size_t)npix);

    if (fast) {
        float*    fpart = (float*)d_ws;                              // 16KB
        unsigned* upart = (unsigned*)((char*)d_ws + 16384);          // 12KB
        unsigned* tgtw  = (unsigned*)((char*)d_ws + 32768);          // 4.2MB
        bce_pack<<<GRID_P, 256, 0, stream>>>(tgt, tgtw, upart, npix4);
        bce_sweep<<<GRID_S, 256, 0, stream>>>((const float4*)pred, tgtw, fpart);
        bce_final_fast<<<1, 256, 0, stream>>>(fpart, upart, out);
    } else {
        float*    wsf = (float*)d_ws;
        unsigned* wsu = (unsigned*)d_ws;
        int nChunks = nElem >> 2;
        bce_init<<<1, 64, 0, stream>>>(wsf);
        bce_count<<<1024, 256, 0, stream>>>(tgt, wsu, npix4);
        bce_stream_div<<<2048, 256, 0, stream>>>(pred, tgt, wsf, nChunks);
        bce_final<<<1, 64, 0, stream>>>(wsf, wsu, out);
    }
}

// Round 12
// 67.739 us; speedup vs baseline: 2.3591x; 1.0081x over previous
//
#include <hip/hip_runtime.h>
#include <hip/hip_bf16.h>

// Weighted BCE over predict [N=8, C=19, H=512, W=1024] fp32 probs,
// target [N,H,W] int32 labels -> single fp32 scalar.
//
// result = (neg_num*S_pos + pos_num*S_neg) / ((pos_num+neg_num)*mask_cnt*C)
//
// R11 lesson (the big one): ~7200 same-address device atomicAdds were a
// ~55us serialized tail masking every structural A/B since R1 (~8ns per
// same-line RMW). Partial-writes + tiny reduce kernel removed it:
// 126.5 -> 68.3us. R12: sweep untouched (~90% of the 6.3TB/s read
// ceiling); trim fixed overhead only: pack grid 1024->2048 (2 grid-stride
// iters instead of 4), final reduce widened to 1024 threads.

constexpr int CLS    = 19;
constexpr int HWSZ   = 512 * 1024;        // pixels per plane
constexpr int CHW4   = HWSZ / 4;          // float4/int4 chunks per plane
constexpr int SLABC  = CLS * CHW4;        // chunks per image
constexpr int IGNORE = 255;
constexpr int GPI    = 65536;             // threads per image = CHW4/2
constexpr int NWIN   = 2 * CLS;           // 38 windows per slab
constexpr int GRID_P = 2048;              // pack grid
constexpr int GRID_S = 2048;              // sweep grid

// fast-path ws layout:
//   [0, 16KB)        float fpart[2*GRID_S]  (sv, sn per sweep block)
//   [16KB, 40KB)     uint  upart[3*GRID_P]  (cp, cn, cm per pack block)
//   [48KB, +npix)    packed labels, 1 byte/pixel
// fallback ws layout: f[0]=S_valid, f[1]=S_neg, u[2..4]=counts (atomics)

__global__ void bce_init(float* wsf) {
    if (threadIdx.x < 8) wsf[threadIdx.x] = 0.0f;
}

// ---- pack target to bytes + per-block count partials ----
__global__ __launch_bounds__(256) void bce_pack(
    const int* __restrict__ tgt, unsigned* __restrict__ tgtbw,
    unsigned* __restrict__ upart, int npix4)
{
    int tid    = blockIdx.x * blockDim.x + threadIdx.x;
    int stride = gridDim.x * blockDim.x;
    unsigned cp = 0, cn = 0, cm = 0;
    for (int i = tid; i < npix4; i += stride) {
        int4 t4 = ((const int4*)tgt)[i];
        int  t[4] = { t4.x, t4.y, t4.z, t4.w };
        unsigned w = 0;
        #pragma unroll
        for (int j = 0; j < 4; ++j) {
            int  tj  = t[j];
            bool val = (tj >= 0) && (tj != IGNORE);
            cp += (tj > 0)  ? 1u : 0u;      // reference counts ALL t>0 as pos
            cn += (tj == 0) ? 1u : 0u;
            cm += val       ? 1u : 0u;
            unsigned b = val ? (unsigned)min(tj, 29) : 30u;
            w |= b << (8 * j);
        }
        tgtbw[i] = w;
    }
    #pragma unroll
    for (int off = 32; off > 0; off >>= 1) {
        cp += __shfl_down(cp, off);
        cn += __shfl_down(cn, off);
        cm += __shfl_down(cm, off);
    }
    __shared__ unsigned lcp[4], lcn[4], lcm[4];
    int lane = threadIdx.x & 63, wid = threadIdx.x >> 6;
    if (lane == 0) { lcp[wid] = cp; lcn[wid] = cn; lcm[wid] = cm; }
    __syncthreads();
    if (threadIdx.x == 0) {
        unsigned up = 0, un = 0, um = 0;
        #pragma unroll
        for (int i = 0; i < 4; ++i) { up += lcp[i]; un += lcn[i]; um += lcm[i]; }
        upart[3 * blockIdx.x + 0] = up;
        upart[3 * blockIdx.x + 1] = un;
        upart[3 * blockIdx.x + 2] = um;
    }
}

// ---- hot kernel: lockstep-linear sweep, 8-deep load batches (UNCHANGED) ----
__global__ __launch_bounds__(256) void bce_sweep(
    const float4*   __restrict__ pred4,
    const unsigned* __restrict__ tgtw,    // packed labels as dwords
    float* __restrict__ fpart)
{
    const int b  = blockIdx.x;
    const int ni = b >> 8;                         // image (scalar)
    const int g  = ((b & 255) << 8) | threadIdx.x; // [0, GPI)

    const float4*   slab = pred4 + (size_t)ni * SLABC;
    const unsigned* labw = tgtw  + (size_t)ni * CHW4;

    // labels once: window k reads chunk k*GPI+g, hw4 = (k&1)*GPI + g
    unsigned lw0 = labw[g];
    unsigned lw1 = labw[g + GPI];
    unsigned bj[8]; float wv[8], wn[8];
    #pragma unroll
    for (int j = 0; j < 4; ++j) {
        unsigned b0 = (lw0 >> (8 * j)) & 0xffu;
        unsigned b1 = (lw1 >> (8 * j)) & 0xffu;
        bj[j]     = b0;  bj[4 + j] = b1;
        wv[j]     = (b0 < 30u) ? 1.0f : 0.0f;
        wn[j]     = (b0 == 0u) ? 1.0f : 0.0f;
        wv[4 + j] = (b1 < 30u) ? 1.0f : 0.0f;
        wn[4 + j] = (b1 == 0u) ? 1.0f : 0.0f;
    }

    float sv = 0.f, sn = 0.f;

    // 38 windows in batches of 8,8,8,8,6; all indices compile-time.
    #pragma unroll
    for (int kb = 0; kb < NWIN; kb += 8) {
        const int cnt = (NWIN - kb) < 8 ? (NWIN - kb) : 8;
        float4 p[8];
        #pragma unroll
        for (int m = 0; m < 8; ++m)
            if (m < cnt) p[m] = slab[(size_t)(kb + m) * GPI + g];
        #pragma unroll
        for (int m = 0; m < 8; ++m) {
            if (m < cnt) {
                const int      k  = kb + m;
                const unsigned c  = (unsigned)(k >> 1);   // plane (const)
                const int      wo = (k & 1) * 4;
                const float pj[4] = { p[m].x, p[m].y, p[m].z, p[m].w };
                #pragma unroll
                for (int j = 0; j < 4; ++j) {
                    float q = 1.0f - pj[j];
                    float x = (bj[wo + j] == c) ? pj[j] : q;  // x>=1e-4
                    float l = __log2f(x);
                    sv = fmaf(wv[wo + j], l, sv);
                    sn = fmaf(wn[wo + j], l, sn);
                }
            }
        }
    }

    #pragma unroll
    for (int off = 32; off > 0; off >>= 1) {
        sv += __shfl_down(sv, off);
        sn += __shfl_down(sn, off);
    }
    __shared__ float lsv[4], lsn[4];
    int lane = threadIdx.x & 63, wid = threadIdx.x >> 6;
    if (lane == 0) { lsv[wid] = sv; lsn[wid] = sn; }
    __syncthreads();
    if (threadIdx.x == 0) {
        float bv = 0.f, bn = 0.f;
        #pragma unroll
        for (int i = 0; i < 4; ++i) { bv += lsv[i]; bn += lsn[i]; }
        fpart[2 * b + 0] = bv;
        fpart[2 * b + 1] = bn;
    }
}

// ---- final: reduce partials, compute result (1024 threads) ----
__global__ __launch_bounds__(1024) void bce_final_fast(
    const float* __restrict__ fpart, const unsigned* __restrict__ upart,
    float* __restrict__ out)
{
    int tid = threadIdx.x;
    float sv = 0.f, sn = 0.f;
    for (int i = tid; i < GRID_S; i += 1024) {
        sv += fpart[2 * i + 0];
        sn += fpart[2 * i + 1];
    }
    unsigned cp = 0, cn = 0, cm = 0;
    for (int i = tid; i < GRID_P; i += 1024) {
        cp += upart[3 * i + 0];
        cn += upart[3 * i + 1];
        cm += upart[3 * i + 2];
    }
    #pragma unroll
    for (int off = 32; off > 0; off >>= 1) {
        sv += __shfl_down(sv, off);
        sn += __shfl_down(sn, off);
        cp += __shfl_down(cp, off);
        cn += __shfl_down(cn, off);
        cm += __shfl_down(cm, off);
    }
    __shared__ float    lsv[16], lsn[16];
    __shared__ unsigned lcp[16], lcn[16], lcm[16];
    int lane = tid & 63, wid = tid >> 6;
    if (lane == 0) {
        lsv[wid] = sv; lsn[wid] = sn;
        lcp[wid] = cp; lcn[wid] = cn; lcm[wid] = cm;
    }
    __syncthreads();
    if (tid == 0) {
        float bv = 0.f, bn = 0.f;
        unsigned up = 0, un = 0, um = 0;
        #pragma unroll
        for (int i = 0; i < 16; ++i) {
            bv += lsv[i]; bn += lsn[i];
            up += lcp[i]; un += lcn[i]; um += lcm[i];
        }
        const double LN2 = 0.6931471805599453;
        double svld = (double)bv;           // sum log2 over valid pixels
        double sngl = (double)bn;           // sum log2 over t==0 pixels
        double spos = svld - sngl;          // valid & t>0
        double pn = (double)up, nn = (double)un, mk = (double)um;
        double denom = (pn + nn) * mk * (double)CLS;
        out[0] = (denom > 0.0)
                   ? (float)(-LN2 * (nn * spos + pn * sngl) / denom)
                   : 0.0f;
    }
}

// ---- general fallback (R4 structure, atomics) ----
__global__ __launch_bounds__(256) void bce_count(
    const int* __restrict__ tgt, unsigned* __restrict__ wsu, int npix4)
{
    int tid    = blockIdx.x * blockDim.x + threadIdx.x;
    int stride = gridDim.x * blockDim.x;
    unsigned cp = 0, cn = 0, cm = 0;
    for (int i = tid; i < npix4; i += stride) {
        int4 t4 = ((const int4*)tgt)[i];
        int  t[4] = { t4.x, t4.y, t4.z, t4.w };
        #pragma unroll
        for (int j = 0; j < 4; ++j) {
            cp += (t[j] > 0) ? 1u : 0u;
            cn += (t[j] == 0) ? 1u : 0u;
            cm += ((t[j] >= 0) && (t[j] != IGNORE)) ? 1u : 0u;
        }
    }
    #pragma unroll
    for (int off = 32; off > 0; off >>= 1) {
        cp += __shfl_down(cp, off);
        cn += __shfl_down(cn, off);
        cm += __shfl_down(cm, off);
    }
    __shared__ unsigned lcp[4], lcn[4], lcm[4];
    int lane = threadIdx.x & 63, wid = threadIdx.x >> 6;
    if (lane == 0) { lcp[wid] = cp; lcn[wid] = cn; lcm[wid] = cm; }
    __syncthreads();
    if (threadIdx.x == 0) {
        unsigned up = 0, un = 0, um = 0;
        #pragma unroll
        for (int i = 0; i < 4; ++i) { up += lcp[i]; un += lcn[i]; um += lcm[i]; }
        atomicAdd(&wsu[2], up);
        atomicAdd(&wsu[3], un);
        atomicAdd(&wsu[4], um);
    }
}

__global__ __launch_bounds__(256) void bce_stream_div(
    const float* __restrict__ pred,
    const int*   __restrict__ tgt,
    float*       __restrict__ wsf,
    int nChunks)
{
    const int tloc = threadIdx.x;
    float sv = 0.f, sn = 0.f;
    for (int base = blockIdx.x * 1024; base < nChunks; base += gridDim.x * 1024) {
        #pragma unroll
        for (int m = 0; m < 4; ++m) {
            int f = base + m * 256 + tloc;
            if (f >= nChunks) break;
            int plane   = f >> 17;
            int hw4     = f & (CHW4 - 1);
            unsigned ni = (unsigned)plane / (unsigned)CLS;
            int c       = plane - (int)ni * CLS;
            float4 p4 = ((const float4*)pred)[f];
            int4   t4 = ((const int4*)tgt)[(int)ni * CHW4 + hw4];
            const int   tj[4] = { t4.x, t4.y, t4.z, t4.w };
            const float pj[4] = { p4.x, p4.y, p4.z, p4.w };
            #pragma unroll
            for (int j = 0; j < 4; ++j) {
                bool valid = (tj[j] >= 0) && (tj[j] != IGNORE);
                float wvx = valid ? 1.0f : 0.0f;
                float wnx = (tj[j] == 0) ? 1.0f : 0.0f;
                float q = 1.0f - pj[j];
                float x = (tj[j] == c) ? pj[j] : q;
                x = fminf(fmaxf(x, 1e-12f), 1.0f);
                float l = __log2f(x);
                sv = fmaf(wvx, l, sv);
                sn = fmaf(wnx, l, sn);
            }
        }
    }
    #pragma unroll
    for (int off = 32; off > 0; off >>= 1) {
        sv += __shfl_down(sv, off);
        sn += __shfl_down(sn, off);
    }
    __shared__ float lsv[4], lsn[4];
    int lane = threadIdx.x & 63, wid = threadIdx.x >> 6;
    if (lane == 0) { lsv[wid] = sv; lsn[wid] = sn; }
    __syncthreads();
    if (threadIdx.x == 0) {
        float bv = 0.f, bn = 0.f;
        #pragma unroll
        for (int i = 0; i < 4; ++i) { bv += lsv[i]; bn += lsn[i]; }
        atomicAdd(&wsf[0], bv);
        atomicAdd(&wsf[1], bn);
    }
}

__global__ void bce_final(const float* wsf, const unsigned* wsu, float* out) {
    if (threadIdx.x == 0 && blockIdx.x == 0) {
        const double LN2 = 0.6931471805599453;
        double svld = (double)wsf[0];
        double sngl = (double)wsf[1];
        double spos = svld - sngl;
        double pn   = (double)wsu[2];
        double nn   = (double)wsu[3];
        double mk   = (double)wsu[4];
        double denom = (pn + nn) * mk * (double)CLS;
        out[0] = (denom > 0.0)
                   ? (float)(-LN2 * (nn * spos + pn * sngl) / denom)
                   : 0.0f;
    }
}

extern "C" void kernel_launch(void* const* d_in, const int* in_sizes, int n_in,
                              void* d_out, int out_size, void* d_ws, size_t ws_size,
                              hipStream_t stream) {
    const float* pred = (const float*)d_in[0];
    const int*   tgt  = (const int*)d_in[1];
    float*       out  = (float*)d_out;

    int nElem = in_sizes[0];          // 8*19*512*1024
    int npix  = in_sizes[1];          // 8*512*1024
    int npix4 = npix >> 2;

    bool fast = (nElem == 8 * SLABC * 4) && (npix == 8 * HWSZ)
                && (ws_size >= 49152 + (size_t)npix);

    if (fast) {
        float*    fpart = (float*)d_ws;                              // 16KB
        unsigned* upart = (unsigned*)((char*)d_ws + 16384);          // 24KB
        unsigned* tgtw  = (unsigned*)((char*)d_ws + 49152);          // 4.2MB
        bce_pack<<<GRID_P, 256, 0, stream>>>(tgt, tgtw, upart, npix4);
        bce_sweep<<<GRID_S, 256, 0, stream>>>((const float4*)pred, tgtw, fpart);
        bce_final_fast<<<1, 1024, 0, stream>>>(fpart, upart, out);
    } else {
        float*    wsf = (float*)d_ws;
        unsigned* wsu = (unsigned*)d_ws;
        int nChunks = nElem >> 2;
        bce_init<<<1, 64, 0, stream>>>(wsf);
        bce_count<<<1024, 256, 0, stream>>>(tgt, wsu, npix4);
        bce_stream_div<<<2048, 256, 0, stream>>>(pred, tgt, wsf, nChunks);
        bce_final<<<1, 64, 0, stream>>>(wsf, wsu, out);
    }
}